// Round 5
// baseline (599.921 us; speedup 1.0000x reference)
//
#include <hip/hip_runtime.h>
#include <hip/hip_fp16.h>

// CapsNet dynamic routing, B=256, P=2048, C=10, OUT=16, IN=8, 3 iters.
// uhat layout: [p][b][c*o] fp16 (R5 change). This makes k_uhat's W indexing
// wave-uniform (scalar s_loads, no VMEM for W) and its stores a single
// 160KB contiguous region per block. k_route reads rows at (p*Bn+b)*ROW
// (320B = 5 full cachelines each), L3-resident after k_uhat.
// k_route: TPB=1024 with __launch_bounds__(1024,4) -> 128-VGPR cap. R4's
// launch_bounds(1024) let the compiler pick a 64-reg budget -> full spill
// (WRITE_SIZE 231MB of scratch). R2 identical story. PIN THE BUDGET.

#define Bn 256
#define Pn 2048
#define Cn 10
#define On 16
#define In 8
#define ROW 160            // Cn*On
#define TPB 1024
#define PAIRS (TPB / 2)    // 512
#define ITERS (Pn / PAIRS) // 4
#define NW (TPB / 64)      // 16 waves
#define CH 5               // c's per half-thread (k_route)
#define HROW 80            // CH*On

typedef _Float16 h2f __attribute__((ext_vector_type(2)));

// ---------------- k_uhat ----------------
// grid = Pn/8 = 256 blocks, 1024 threads. Block owns 8 consecutive p, all b.
// t = b + 256*q ; q = co-quarter (wave-uniform -> readfirstlane -> SGPR so
// W loads stay scalar). Thread computes 40 co-cells for (b, each of 8 p).
__global__ __launch_bounds__(1024, 4) void k_uhat(const float* __restrict__ u,
                                                  const float* __restrict__ W,
                                                  __half* __restrict__ uhat) {
  const int t = threadIdx.x;
  const int b = t & 255;
  const int q = __builtin_amdgcn_readfirstlane(t >> 8); // wave-uniform quarter
  const int p0 = blockIdx.x * 8;

#pragma unroll
  for (int pl = 0; pl < 8; ++pl) {
    const int p = p0 + pl;
    const float4* up = reinterpret_cast<const float4*>(u + ((size_t)b * Pn + p) * In);
    float4 x0 = up[0], x1 = up[1];
    const float uu[8] = {x0.x, x0.y, x0.z, x0.w, x1.x, x1.y, x1.z, x1.w};
    const float* wr = W + (size_t)p * (Cn * On * In) + q * 320; // q*40 cells *8i
    __half* orow = uhat + ((size_t)p * Bn + b) * ROW + q * 40;
#pragma unroll
    for (int ch = 0; ch < 5; ++ch) { // 8 co-cells -> 16B store
      union { float4 f; __half2 h2[4]; } ov;
#pragma unroll
      for (int j = 0; j < 4; ++j) {
        const float* w0 = wr + (ch * 8 + 2 * j) * 8; // uniform addr -> s_load
        float d0 = w0[0] * uu[0], d1 = w0[8] * uu[0];
#pragma unroll
        for (int i = 1; i < 8; ++i) {
          d0 = __builtin_fmaf(w0[i], uu[i], d0);
          d1 = __builtin_fmaf(w0[8 + i], uu[i], d1);
        }
        ov.h2[j] = __floats2half2_rn(d0, d1);
      }
      *reinterpret_cast<float4*>(orow + ch * 8) = ov.f;
    }
  }
}

// ---------------- k_route ----------------
__device__ __forceinline__ void reduce_squash(float (&acc)[CH][On], float scale,
                                              int tid, int lane, int w, int h,
                                              float (*s_red)[ROW], float* s_lds,
                                              float* v_lds, __half2 (*v_h2)[8]) {
#pragma unroll
  for (int k = 0; k < HROW; ++k) {
    float x = acc[k >> 4][k & 15];
#pragma unroll
    for (int off = 2; off <= 32; off <<= 1) x += __shfl_xor(x, off, 64);
    if ((lane >> 1) == (k & 31)) s_red[w][h * HROW + k] = x;
  }
  __syncthreads();
  if (tid < ROW) {
    float tsum = 0.f;
#pragma unroll
    for (int ww = 0; ww < NW; ++ww) tsum += s_red[ww][tid];
    s_lds[tid] = scale * tsum;
  }
  __syncthreads();
  if (tid < Cn) {
    float sq = 0.f;
#pragma unroll
    for (int o = 0; o < On; ++o) {
      float x = s_lds[tid * On + o];
      sq += x * x;
    }
    float sc = (sq / (1.f + sq)) / sqrtf(sq + 1e-9f);
#pragma unroll
    for (int o = 0; o < On; ++o) v_lds[tid * On + o] = sc * s_lds[tid * On + o];
#pragma unroll
    for (int o2 = 0; o2 < 8; ++o2)
      v_h2[tid][o2] = __floats2half2_rn(v_lds[tid * On + 2 * o2],
                                        v_lds[tid * On + 2 * o2 + 1]);
  }
  __syncthreads();
}

__global__ __launch_bounds__(TPB, 4) void k_route(const __half* __restrict__ uhat,
                                                  float* __restrict__ out) {
  __shared__ __half lg_lds[Pn][2][CH]; // 40960 B
  __shared__ float s_red[NW][ROW];     // 10240 B
  __shared__ float s_lds[ROW];
  __shared__ float v_lds[ROW];
  __shared__ __half2 v_h2[Cn][8];
  const int b = blockIdx.x;
  const int tid = threadIdx.x;
  const int lane = tid & 63;
  const int w = tid >> 6;
  const int h = tid & 1;   // c-half this thread owns
  const int pr = tid >> 1; // pair index in [0,512)

  float acc[CH][On];

  // ---- PASS 1: weights uniform 0.1 ----
#pragma unroll
  for (int kc = 0; kc < CH; ++kc)
#pragma unroll
    for (int o = 0; o < On; ++o) acc[kc][o] = 0.f;
  for (int it = 0; it < ITERS; ++it) {
    const int p = pr + PAIRS * it;
    const __half* row = uhat + ((size_t)p * Bn + b) * ROW + h * HROW;
#pragma unroll
    for (int kc = 0; kc < CH; ++kc) {
      union { float4 f[2]; __half hh[16]; } qd;
      qd.f[0] = *reinterpret_cast<const float4*>(row + kc * 16);
      qd.f[1] = *reinterpret_cast<const float4*>(row + kc * 16 + 8);
#pragma unroll
      for (int o = 0; o < On; ++o) acc[kc][o] += __half2float(qd.hh[o]);
    }
  }
  reduce_squash(acc, 0.1f, tid, lane, w, h, s_red, s_lds, v_lds, v_h2);

  // ---- PASSES 2,3 (b-update folded into softmax) ----
  for (int pass = 0; pass < 2; ++pass) {
#pragma unroll
    for (int kc = 0; kc < CH; ++kc)
#pragma unroll
      for (int o = 0; o < On; ++o) acc[kc][o] = 0.f;
    for (int it = 0; it < ITERS; ++it) {
      const int p = pr + PAIRS * it;
      const __half* row = uhat + ((size_t)p * Bn + b) * ROW + h * HROW;
      float lg[CH];
#pragma unroll
      for (int kc = 0; kc < CH; ++kc) {
        union { float4 f[2]; h2f hh2[8]; } qd;
        qd.f[0] = *reinterpret_cast<const float4*>(row + kc * 16);
        qd.f[1] = *reinterpret_cast<const float4*>(row + kc * 16 + 8);
        float d = 0.f;
#pragma unroll
        for (int o2 = 0; o2 < 8; ++o2) {
          h2f vv = *reinterpret_cast<const h2f*>(&v_h2[h * CH + kc][o2]); // uniform: LDS broadcast
          d = __builtin_amdgcn_fdot2(qd.hh2[o2], vv, d, false);
        }
        lg[kc] = (pass == 0) ? d : (d + __half2float(lg_lds[p][h][kc]));
      }
      if (pass == 0) {
#pragma unroll
        for (int kc = 0; kc < CH; ++kc) lg_lds[p][h][kc] = __float2half(lg[kc]);
      }
      // softmax across both halves via 2 shuffles
      float m = lg[0];
#pragma unroll
      for (int kc = 1; kc < CH; ++kc) m = fmaxf(m, lg[kc]);
      m = fmaxf(m, __shfl_xor(m, 1, 64));
      float e[CH], ssum = 0.f;
#pragma unroll
      for (int kc = 0; kc < CH; ++kc) {
        e[kc] = __expf(lg[kc] - m);
        ssum += e[kc];
      }
      ssum += __shfl_xor(ssum, 1, 64);
      const float inv = 1.f / ssum;
#pragma unroll
      for (int kc = 0; kc < CH; ++kc) {
        union { float4 f[2]; __half hh[16]; } qd;
        qd.f[0] = *reinterpret_cast<const float4*>(row + kc * 16); // L1-hot reload
        qd.f[1] = *reinterpret_cast<const float4*>(row + kc * 16 + 8);
        const float cv = e[kc] * inv;
#pragma unroll
        for (int o = 0; o < On; ++o)
          acc[kc][o] = __builtin_fmaf(cv, __half2float(qd.hh[o]), acc[kc][o]);
      }
    }
    reduce_squash(acc, 1.0f, tid, lane, w, h, s_red, s_lds, v_lds, v_h2);
  }

  if (tid < ROW) out[(size_t)b * ROW + tid] = v_lds[tid];
}

extern "C" void kernel_launch(void* const* d_in, const int* in_sizes, int n_in,
                              void* d_out, int out_size, void* d_ws, size_t ws_size,
                              hipStream_t stream) {
  (void)in_sizes; (void)n_in; (void)out_size;
  const float* u = (const float*)d_in[0];
  const float* W = (const float*)d_in[1];
  float* out = (float*)d_out;
  __half* uhat = (__half*)d_ws;
  const size_t need = (size_t)Bn * Pn * Cn * On * sizeof(__half);
  if (ws_size < need) return; // needs ~168 MB scratch
  k_uhat<<<Pn / 8, 1024, 0, stream>>>(u, W, uhat);
  k_route<<<Bn, TPB, 0, stream>>>(uhat, out);
}

// Round 6
// 337.927 us; speedup vs baseline: 1.7753x; 1.7753x over previous
//
#include <hip/hip_runtime.h>
#include <hip/hip_fp16.h>

// CapsNet dynamic routing, B=256, P=2048, C=10, OUT=16, IN=8, 3 iters.
// uhat layout: [p][b][co] fp16 in d_ws (167.8 MB).
//   k_uhat: R3's proven form (block=p, thread=b, W wave-uniform -> scalar
//     loads) but stores are now one contiguous 80KB region per block
//     (R3's [b][p] layout scattered 256 x 320B regions -> 1.3 TB/s writes).
//   k_route: R3's proven TPB=512 form (VGPR budget semantics WORK at 512;
//     TPB=1024 pinned a 64-reg cap twice -> full spill, R4/R5). blockIdx
//     swizzle b=(x&31)*8+(x>>5) puts the 8 b's sharing each 128B uhat line
//     on one XCD (XCD = blockIdx%8) -> scattered reads become L2 hits.
//     Row chunks kept live in regs across dot->softmax->acc (no reload).

#define Bn 256
#define Pn 2048
#define Cn 10
#define On 16
#define In 8
#define ROW 160            // Cn*On
#define TPB 512
#define PAIRS (TPB / 2)    // 256
#define ITERS (Pn / PAIRS) // 8
#define NW (TPB / 64)      // 8 waves
#define CH 5               // c's per half-thread
#define HROW 80            // CH*On

typedef _Float16 h2f __attribute__((ext_vector_type(2)));
union RowU { float4 f[2]; h2f hh2[8]; __half hh[16]; };

// ---------------- k_uhat ----------------
// grid = Pn, TPB = 256 (thread = b). W base uniform per block -> scalar path.
// Output row (p*Bn+b)*ROW: block writes 256*320B = 80KB contiguous.
__global__ __launch_bounds__(256) void k_uhat(const float* __restrict__ u,
                                              const float* __restrict__ W,
                                              __half* __restrict__ uhat) {
  const int p = blockIdx.x;
  const int b = threadIdx.x;
  const float4* up = reinterpret_cast<const float4*>(u + ((size_t)b * Pn + p) * In);
  float4 x0 = up[0], x1 = up[1];
  const float uu[8] = {x0.x, x0.y, x0.z, x0.w, x1.x, x1.y, x1.z, x1.w};
  const float* wr = W + (size_t)p * (Cn * On * In); // uniform -> s_load
  __half* orow = uhat + ((size_t)p * Bn + b) * ROW;

#pragma unroll
  for (int ch = 0; ch < 20; ++ch) { // 8 co-cells -> one 16B store
    union { float4 f; __half2 h2[4]; } ov;
#pragma unroll
    for (int j = 0; j < 4; ++j) {
      const float* w0 = wr + (ch * 8 + 2 * j) * 8;
      float d0 = w0[0] * uu[0], d1 = w0[8] * uu[0];
#pragma unroll
      for (int i = 1; i < 8; ++i) {
        d0 = __builtin_fmaf(w0[i], uu[i], d0);
        d1 = __builtin_fmaf(w0[8 + i], uu[i], d1);
      }
      ov.h2[j] = __floats2half2_rn(d0, d1);
    }
    *reinterpret_cast<float4*>(orow + ch * 8) = ov.f;
  }
}

// ---------------- k_route ----------------
__device__ __forceinline__ void reduce_squash(float (&acc)[CH][On], float scale,
                                              int tid, int lane, int w, int h,
                                              float (*s_red)[ROW], float* s_lds,
                                              float* v_lds, __half2 (*v_h2)[8]) {
#pragma unroll
  for (int k = 0; k < HROW; ++k) {
    float x = acc[k >> 4][k & 15];
#pragma unroll
    for (int off = 2; off <= 32; off <<= 1) x += __shfl_xor(x, off, 64);
    if ((lane >> 1) == (k & 31)) s_red[w][h * HROW + k] = x;
  }
  __syncthreads();
  if (tid < ROW) {
    float tsum = 0.f;
#pragma unroll
    for (int ww = 0; ww < NW; ++ww) tsum += s_red[ww][tid];
    s_lds[tid] = scale * tsum;
  }
  __syncthreads();
  if (tid < Cn) {
    float sq = 0.f;
#pragma unroll
    for (int o = 0; o < On; ++o) {
      float x = s_lds[tid * On + o];
      sq += x * x;
    }
    float sc = (sq / (1.f + sq)) / sqrtf(sq + 1e-9f);
#pragma unroll
    for (int o = 0; o < On; ++o) v_lds[tid * On + o] = sc * s_lds[tid * On + o];
#pragma unroll
    for (int o2 = 0; o2 < 8; ++o2)
      v_h2[tid][o2] = __floats2half2_rn(v_lds[tid * On + 2 * o2],
                                        v_lds[tid * On + 2 * o2 + 1]);
  }
  __syncthreads();
}

__global__ __launch_bounds__(TPB, 2) void k_route(const __half* __restrict__ uhat,
                                                  float* __restrict__ out) {
  __shared__ __half lg_lds[Pn][2][CH]; // 40960 B
  __shared__ float s_red[NW][ROW];     // 5120 B
  __shared__ float s_lds[ROW];
  __shared__ float v_lds[ROW];
  __shared__ __half2 v_h2[Cn][8];
  // swizzle: the 8 b's sharing each 128B uhat cacheline land on one XCD
  const int x = blockIdx.x;
  const int b = (x & 31) * 8 + (x >> 5);
  const int tid = threadIdx.x;
  const int lane = tid & 63;
  const int w = tid >> 6;
  const int h = tid & 1;   // c-half this thread owns
  const int pr = tid >> 1; // pair index in [0,256)

  float acc[CH][On];

  // ---- PASS 1: weights uniform 0.1 ----
#pragma unroll
  for (int kc = 0; kc < CH; ++kc)
#pragma unroll
    for (int o = 0; o < On; ++o) acc[kc][o] = 0.f;
  for (int it = 0; it < ITERS; ++it) {
    const int p = pr + PAIRS * it;
    const __half* row = uhat + ((size_t)p * Bn + b) * ROW + h * HROW;
#pragma unroll
    for (int kc = 0; kc < CH; ++kc) {
      RowU q;
      q.f[0] = *reinterpret_cast<const float4*>(row + kc * 16);
      q.f[1] = *reinterpret_cast<const float4*>(row + kc * 16 + 8);
#pragma unroll
      for (int o = 0; o < On; ++o) acc[kc][o] += __half2float(q.hh[o]);
    }
  }
  reduce_squash(acc, 0.1f, tid, lane, w, h, s_red, s_lds, v_lds, v_h2);

  // ---- PASSES 2,3 (b-update folded into softmax) ----
  for (int pass = 0; pass < 2; ++pass) {
#pragma unroll
    for (int kc = 0; kc < CH; ++kc)
#pragma unroll
      for (int o = 0; o < On; ++o) acc[kc][o] = 0.f;
    for (int it = 0; it < ITERS; ++it) {
      const int p = pr + PAIRS * it;
      const __half* row = uhat + ((size_t)p * Bn + b) * ROW + h * HROW;
      RowU q[CH]; // kept live through dot -> softmax -> acc (no reload)
      float lg[CH];
#pragma unroll
      for (int kc = 0; kc < CH; ++kc) {
        q[kc].f[0] = *reinterpret_cast<const float4*>(row + kc * 16);
        q[kc].f[1] = *reinterpret_cast<const float4*>(row + kc * 16 + 8);
        float d = 0.f;
#pragma unroll
        for (int o2 = 0; o2 < 8; ++o2) {
          h2f vv = *reinterpret_cast<const h2f*>(&v_h2[h * CH + kc][o2]); // uniform: LDS broadcast
          d = __builtin_amdgcn_fdot2(q[kc].hh2[o2], vv, d, false);
        }
        lg[kc] = (pass == 0) ? d : (d + __half2float(lg_lds[p][h][kc]));
      }
      if (pass == 0) {
#pragma unroll
        for (int kc = 0; kc < CH; ++kc) lg_lds[p][h][kc] = __float2half(lg[kc]);
      }
      // softmax across both halves via 2 shuffles
      float m = lg[0];
#pragma unroll
      for (int kc = 1; kc < CH; ++kc) m = fmaxf(m, lg[kc]);
      m = fmaxf(m, __shfl_xor(m, 1, 64));
      float e[CH], ssum = 0.f;
#pragma unroll
      for (int kc = 0; kc < CH; ++kc) {
        e[kc] = __expf(lg[kc] - m);
        ssum += e[kc];
      }
      ssum += __shfl_xor(ssum, 1, 64);
      const float inv = 1.f / ssum;
#pragma unroll
      for (int kc = 0; kc < CH; ++kc) {
        const float cv = e[kc] * inv;
#pragma unroll
        for (int o = 0; o < On; ++o)
          acc[kc][o] = __builtin_fmaf(cv, __half2float(q[kc].hh[o]), acc[kc][o]);
      }
    }
    reduce_squash(acc, 1.0f, tid, lane, w, h, s_red, s_lds, v_lds, v_h2);
  }

  if (tid < ROW) out[(size_t)b * ROW + tid] = v_lds[tid];
}

extern "C" void kernel_launch(void* const* d_in, const int* in_sizes, int n_in,
                              void* d_out, int out_size, void* d_ws, size_t ws_size,
                              hipStream_t stream) {
  (void)in_sizes; (void)n_in; (void)out_size;
  const float* u = (const float*)d_in[0];
  const float* W = (const float*)d_in[1];
  float* out = (float*)d_out;
  __half* uhat = (__half*)d_ws;
  const size_t need = (size_t)Bn * Pn * Cn * On * sizeof(__half);
  if (ws_size < need) return; // needs ~168 MB scratch
  k_uhat<<<Pn, 256, 0, stream>>>(u, W, uhat);
  k_route<<<Bn, TPB, 0, stream>>>(uhat, out);
}

// Round 7
// 264.136 us; speedup vs baseline: 2.2713x; 1.2794x over previous
//
#include <hip/hip_runtime.h>
#include <hip/hip_fp16.h>

// CapsNet dynamic routing, B=256, P=2048, C=10, OUT=16, IN=8, 3 iters.
// uhat layout: [p][h][b][80co] fp16 (h = c-half). Dense unit per (p,h) is
// 256*160B = 40KB contiguous.
// k_uhat: R6's form (block=p, thread=b, wave-uniform W -> s_loads) but each
//   wave stages its 64 half-rows in LDS (176B padded stride) and rewrites
//   them as 1KB-dense wave stores. R6 stored 16B chunks at 320B stride ->
//   partial-line RMW, WRITE_SIZE 400+MB vs 168 ideal -> 150us. No
//   __syncthreads: DS ops within a wave are ordered (wave-local slabs).
// k_route: R6 verbatim (TPB=512 - the only TPB where the VGPR budget
//   behaves; 1024 pinned 64 regs twice -> spill), only row addressing
//   updated to the new layout.

#define Bn 256
#define Pn 2048
#define Cn 10
#define On 16
#define In 8
#define ROW 160            // Cn*On
#define TPB 512
#define PAIRS (TPB / 2)    // 256
#define ITERS (Pn / PAIRS) // 8
#define NW (TPB / 64)      // 8 waves
#define CH 5               // c's per half-thread
#define HROW 80            // CH*On

typedef _Float16 h2f __attribute__((ext_vector_type(2)));
union RowU { float4 f[2]; h2f hh2[8]; __half hh[16]; };

// ---------------- k_uhat ----------------
// grid = Pn, TPB = 256 (thread = b). W base uniform per block -> scalar path.
__global__ __launch_bounds__(256) void k_uhat(const float* __restrict__ u,
                                              const float* __restrict__ W,
                                              __half* __restrict__ uhat) {
  __shared__ __half st[4][64 * 88]; // 88 halves = 176B padded stage stride; 45056B
  const int p = blockIdx.x;
  const int t = threadIdx.x;
  const int w = t >> 6;
  const int lane = t & 63;
  const float4* up = reinterpret_cast<const float4*>(u + ((size_t)t * Pn + p) * In);
  float4 x0 = up[0], x1 = up[1];
  const float uu[8] = {x0.x, x0.y, x0.z, x0.w, x1.x, x1.y, x1.z, x1.w};
  const float* wr = W + (size_t)p * (Cn * On * In); // uniform -> s_load

  __half* srow = &st[w][lane * 88];
  const __half* sbase = st[w];

  for (int h = 0; h < 2; ++h) {
    // compute this b's half-row (80 cells = 160B) into the wave slab
#pragma unroll
    for (int ch = 0; ch < 10; ++ch) {
      union { float4 f; __half2 h2[4]; } ov;
#pragma unroll
      for (int j = 0; j < 4; ++j) {
        const float* w0 = wr + (h * 80 + ch * 8 + 2 * j) * 8;
        float d0 = w0[0] * uu[0], d1 = w0[8] * uu[0];
#pragma unroll
        for (int i = 1; i < 8; ++i) {
          d0 = __builtin_fmaf(w0[i], uu[i], d0);
          d1 = __builtin_fmaf(w0[8 + i], uu[i], d1);
        }
        ov.h2[j] = __floats2half2_rn(d0, d1);
      }
      *reinterpret_cast<float4*>(srow + ch * 8) = ov.f;
    }
    // rewrite the wave's 64 half-rows as 10 dense 1KB wave-stores
    __half* gbase = uhat + (((size_t)p * 2 + h) * Bn + w * 64) * HROW;
#pragma unroll
    for (int i = 0; i < 10; ++i) {
      const int f = lane + 64 * i;     // flat 16B-chunk index in the 10KB region
      const int r = f / 10;            // source b-row in slab
      const int c = f - r * 10;        // chunk within row
      float4 val = *reinterpret_cast<const float4*>(sbase + r * 88 + c * 8);
      *reinterpret_cast<float4*>(gbase + f * 8) = val;
    }
  }
}

// ---------------- k_route ----------------
__device__ __forceinline__ void reduce_squash(float (&acc)[CH][On], float scale,
                                              int tid, int lane, int w, int h,
                                              float (*s_red)[ROW], float* s_lds,
                                              float* v_lds, __half2 (*v_h2)[8]) {
#pragma unroll
  for (int k = 0; k < HROW; ++k) {
    float x = acc[k >> 4][k & 15];
#pragma unroll
    for (int off = 2; off <= 32; off <<= 1) x += __shfl_xor(x, off, 64);
    if ((lane >> 1) == (k & 31)) s_red[w][h * HROW + k] = x;
  }
  __syncthreads();
  if (tid < ROW) {
    float tsum = 0.f;
#pragma unroll
    for (int ww = 0; ww < NW; ++ww) tsum += s_red[ww][tid];
    s_lds[tid] = scale * tsum;
  }
  __syncthreads();
  if (tid < Cn) {
    float sq = 0.f;
#pragma unroll
    for (int o = 0; o < On; ++o) {
      float x = s_lds[tid * On + o];
      sq += x * x;
    }
    float sc = (sq / (1.f + sq)) / sqrtf(sq + 1e-9f);
#pragma unroll
    for (int o = 0; o < On; ++o) v_lds[tid * On + o] = sc * s_lds[tid * On + o];
#pragma unroll
    for (int o2 = 0; o2 < 8; ++o2)
      v_h2[tid][o2] = __floats2half2_rn(v_lds[tid * On + 2 * o2],
                                        v_lds[tid * On + 2 * o2 + 1]);
  }
  __syncthreads();
}

__global__ __launch_bounds__(TPB, 2) void k_route(const __half* __restrict__ uhat,
                                                  float* __restrict__ out) {
  __shared__ __half lg_lds[Pn][2][CH]; // 40960 B
  __shared__ float s_red[NW][ROW];     // 5120 B
  __shared__ float s_lds[ROW];
  __shared__ float v_lds[ROW];
  __shared__ __half2 v_h2[Cn][8];
  // swizzle: adjacent-b blocks land on one XCD for L2 line sharing
  const int x = blockIdx.x;
  const int b = (x & 31) * 8 + (x >> 5);
  const int tid = threadIdx.x;
  const int lane = tid & 63;
  const int w = tid >> 6;
  const int h = tid & 1;   // c-half this thread owns
  const int pr = tid >> 1; // pair index in [0,256)

  float acc[CH][On];

  // ---- PASS 1: weights uniform 0.1 ----
#pragma unroll
  for (int kc = 0; kc < CH; ++kc)
#pragma unroll
    for (int o = 0; o < On; ++o) acc[kc][o] = 0.f;
  for (int it = 0; it < ITERS; ++it) {
    const int p = pr + PAIRS * it;
    const __half* row = uhat + (((size_t)p * 2 + h) * Bn + b) * HROW;
#pragma unroll
    for (int kc = 0; kc < CH; ++kc) {
      RowU q;
      q.f[0] = *reinterpret_cast<const float4*>(row + kc * 16);
      q.f[1] = *reinterpret_cast<const float4*>(row + kc * 16 + 8);
#pragma unroll
      for (int o = 0; o < On; ++o) acc[kc][o] += __half2float(q.hh[o]);
    }
  }
  reduce_squash(acc, 0.1f, tid, lane, w, h, s_red, s_lds, v_lds, v_h2);

  // ---- PASSES 2,3 (b-update folded into softmax) ----
  for (int pass = 0; pass < 2; ++pass) {
#pragma unroll
    for (int kc = 0; kc < CH; ++kc)
#pragma unroll
      for (int o = 0; o < On; ++o) acc[kc][o] = 0.f;
    for (int it = 0; it < ITERS; ++it) {
      const int p = pr + PAIRS * it;
      const __half* row = uhat + (((size_t)p * 2 + h) * Bn + b) * HROW;
      RowU q[CH]; // kept live through dot -> softmax -> acc (no reload)
      float lg[CH];
#pragma unroll
      for (int kc = 0; kc < CH; ++kc) {
        q[kc].f[0] = *reinterpret_cast<const float4*>(row + kc * 16);
        q[kc].f[1] = *reinterpret_cast<const float4*>(row + kc * 16 + 8);
        float d = 0.f;
#pragma unroll
        for (int o2 = 0; o2 < 8; ++o2) {
          h2f vv = *reinterpret_cast<const h2f*>(&v_h2[h * CH + kc][o2]); // uniform: LDS broadcast
          d = __builtin_amdgcn_fdot2(q[kc].hh2[o2], vv, d, false);
        }
        lg[kc] = (pass == 0) ? d : (d + __half2float(lg_lds[p][h][kc]));
      }
      if (pass == 0) {
#pragma unroll
        for (int kc = 0; kc < CH; ++kc) lg_lds[p][h][kc] = __float2half(lg[kc]);
      }
      // softmax across both halves via 2 shuffles
      float m = lg[0];
#pragma unroll
      for (int kc = 1; kc < CH; ++kc) m = fmaxf(m, lg[kc]);
      m = fmaxf(m, __shfl_xor(m, 1, 64));
      float e[CH], ssum = 0.f;
#pragma unroll
      for (int kc = 0; kc < CH; ++kc) {
        e[kc] = __expf(lg[kc] - m);
        ssum += e[kc];
      }
      ssum += __shfl_xor(ssum, 1, 64);
      const float inv = 1.f / ssum;
#pragma unroll
      for (int kc = 0; kc < CH; ++kc) {
        const float cv = e[kc] * inv;
#pragma unroll
        for (int o = 0; o < On; ++o)
          acc[kc][o] = __builtin_fmaf(cv, __half2float(q[kc].hh[o]), acc[kc][o]);
      }
    }
    reduce_squash(acc, 1.0f, tid, lane, w, h, s_red, s_lds, v_lds, v_h2);
  }

  if (tid < ROW) out[(size_t)b * ROW + tid] = v_lds[tid];
}

extern "C" void kernel_launch(void* const* d_in, const int* in_sizes, int n_in,
                              void* d_out, int out_size, void* d_ws, size_t ws_size,
                              hipStream_t stream) {
  (void)in_sizes; (void)n_in; (void)out_size;
  const float* u = (const float*)d_in[0];
  const float* W = (const float*)d_in[1];
  float* out = (float*)d_out;
  __half* uhat = (__half*)d_ws;
  const size_t need = (size_t)Bn * Pn * Cn * On * sizeof(__half);
  if (ws_size < need) return; // needs ~168 MB scratch
  k_uhat<<<Pn, 256, 0, stream>>>(u, W, uhat);
  k_route<<<Bn, TPB, 0, stream>>>(uhat, out);
}